// Round 6
// baseline (922.205 us; speedup 1.0000x reference)
//
#include <hip/hip_runtime.h>
#include <hip/hip_bf16.h>

#define BB 32
#define LL 200
#define DD 768
#define SS 1556
#define MAXM 6400   // per-kk flattened row capacity (32 * (199-kk) < 6400)
#define NTILES_MAX 2400

typedef __attribute__((ext_vector_type(8))) short bf16x8;   // 8 bf16 = 4 VGPRs (MFMA A/B frag)
typedef __attribute__((ext_vector_type(4))) float floatx4;  // MFMA C/D frag

__device__ __forceinline__ float bf2f(ushort u){
    union { unsigned int i; float f; } v; v.i = ((unsigned int)u) << 16; return v.f;
}
__device__ __forceinline__ ushort f2bf(float f){
    union { float f; unsigned int i; } v; v.f = f;
    unsigned int x = v.i;
    return (ushort)((x + 0x7FFFu + ((x >> 16) & 1u)) >> 16);  // RNE, inputs finite
}

// ---------------------------------------------------------------------------
// Kernel 1: prep — dtype detect + per-batch offsets + row maps + tile list.
// One block, 256 threads. Tile list is LPT-ordered (kk=8 first) and bucketed
// by (kk*6+nt)%8 interleaved at stride 8 -> tiles sharing a B n-strip land on
// the same XCD (blockIdx%8 heuristic) for L2 reuse.
// ---------------------------------------------------------------------------
__global__ void prep_kernel(const unsigned int* __restrict__ feat_raw,
                            const int* __restrict__ mask,
                            int* __restrict__ flag, int* __restrict__ offs,
                            int* __restrict__ pfx, int* __restrict__ amap,
                            int* __restrict__ omap, int* __restrict__ tiles,
                            int use_full){
    __shared__ int cnt_s;
    __shared__ int offs_s[32*9];
    __shared__ int P_s[7][33];
    const int tid = threadIdx.x;

    // --- phase 1: dtype detect + mask sums ---
    if (tid == 0) cnt_s = 0;
    __syncthreads();
    int c = 0;
    for (int i = tid; i < 4096; i += 256){
        unsigned int w = feat_raw[i];
        unsigned int e = (w >> 7) & 0xFFu;
        if (e >= 100u && e <= 150u) c++;
    }
    atomicAdd(&cnt_s, c);

    int b = tid >> 3, sub = tid & 7;
    int s = 0;
    for (int i = sub; i < LL; i += 8) s += mask[b*LL + i];
    s += __shfl_down(s, 4, 8);
    s += __shfl_down(s, 2, 8);
    s += __shfl_down(s, 1, 8);
    if (sub == 0){
        int n = s, cum = 0;
        offs_s[b*9 + 0] = 0;
        for (int j = 0; j < 8; ++j){
            int cc = n - j - 2; if (cc < 0) cc = 0;
            cum += cc;
            offs_s[b*9 + j + 1] = cum;
        }
    }
    __syncthreads();

    // --- phase 2: publish flag/offs, P prefixes, prefill tiles ---
    if (tid == 0) *flag = (cnt_s > 2457) ? 1 : 0;
    for (int i = tid; i < 288; i += 256) offs[i] = offs_s[i];   // R5 BUG FIX: was `if (tid < 288)` with 256 threads -> entries 256..287 left poisoned
    if (tid < 7){
        int kk = tid + 2, acc = 0;
        P_s[tid][0] = 0;
        for (int bb = 0; bb < 32; ++bb){
            acc += offs_s[bb*9 + kk] - offs_s[bb*9 + kk - 1];
            P_s[tid][bb + 1] = acc;
        }
        if (use_full) pfx[tid*33 + 32] = acc;
    }
    if (use_full)
        for (int i = tid; i < NTILES_MAX; i += 256) tiles[i] = -1;
    __syncthreads();
    if (!use_full) return;

    // --- phase 3: row maps (all threads) ---
    for (int kx = 0; kx < 7; ++kx){
        const int kk = kx + 2;
        const int Mtot = P_s[kx][32];
        for (int r = tid; r < MAXM; r += 256){
            int bcnt = 0;
            #pragma unroll
            for (int i = 1; i <= 32; ++i) bcnt += (P_s[kx][i] <= r) ? 1 : 0;
            int bb = bcnt < 32 ? bcnt : 31;
            int larow = (r < Mtot) ? (r - P_s[kx][bb]) : 0;
            amap[kx*MAXM + r] = bb*LL + larow + 1;
            omap[kx*MAXM + r] = bb*SS + offs_s[bb*9 + kk - 1] + larow;
        }
    }

    // --- phase 4: tile list (thread 0, serial ~1100 iters) ---
    if (tid == 0){
        int bc[8] = {0,0,0,0,0,0,0,0};
        for (int kx = 6; kx >= 0; --kx){              // heavy kk first (LPT)
            int mts = (P_s[kx][32] + 127) >> 7;
            for (int mt = 0; mt < mts; ++mt)
                for (int nt = 0; nt < 6; ++nt){
                    int x = (kx*6 + nt) & 7;          // XCD bucket
                    tiles[x + 8*bc[x]] = (kx << 16) | (mt << 8) | nt;
                    bc[x]++;
                }
        }
    }
}

// ---------------------------------------------------------------------------
// Kernel 2: ALL widths' weight repack in ONE launch. grid=(192, 7).
// w_kk [768][768][kk] (O,I,T) -> Bp_kk[jb][o][jj], j=jb*8+jj=t*768+i.
// ---------------------------------------------------------------------------
__global__ void repack2_kernel(const void* __restrict__ w2, const void* __restrict__ w3,
                               const void* __restrict__ w4, const void* __restrict__ w5,
                               const void* __restrict__ w6, const void* __restrict__ w7,
                               const void* __restrict__ w8,
                               const void* __restrict__ b2, const void* __restrict__ b3,
                               const void* __restrict__ b4, const void* __restrict__ b5,
                               const void* __restrict__ b6, const void* __restrict__ b7,
                               const void* __restrict__ b8,
                               ushort* __restrict__ BpAll, float* __restrict__ biasF,
                               const int* __restrict__ flag){
    const size_t PRE[7] = {0, 2, 5, 9, 14, 20, 27};
    const int kkidx = blockIdx.y;
    const int kk = kkidx + 2;
    const void* w  = kkidx==0?w2:kkidx==1?w3:kkidx==2?w4:kkidx==3?w5:kkidx==4?w6:kkidx==5?w7:w8;
    const void* bv = kkidx==0?b2:kkidx==1?b3:kkidx==2?b4:kkidx==3?b5:kkidx==4?b6:kkidx==5?b7:b8;
    ushort* Bp = BpAll + PRE[kkidx]*589824;

    const int bfm = *flag;
    __shared__ ushort lds[24576];
    const int tid = threadIdx.x;
    const int ob  = blockIdx.x;
    const int rowlen = DD * kk;
    const int nelem  = 4 * rowlen;

    if (bfm){
        const ushort* src = (const ushort*)w + (size_t)ob * nelem;
        const int nch = nelem >> 3;
        for (int c = tid; c < nch; c += 256)
            __builtin_memcpy(lds + c*8, src + c*8, 16);
        if (ob == 0)
            for (int i = tid; i < DD; i += 256) biasF[kkidx*DD + i] = bf2f(((const ushort*)bv)[i]);
    } else {
        const float* src = (const float*)w + (size_t)ob * nelem;
        const int nch = nelem >> 2;
        for (int c = tid; c < nch; c += 256){
            float t4[4];
            __builtin_memcpy(t4, src + c*4, 16);
            #pragma unroll
            for (int j2 = 0; j2 < 4; ++j2) lds[c*4 + j2] = f2bf(t4[j2]);
        }
        if (ob == 0)
            for (int i = tid; i < DD; i += 256) biasF[kkidx*DD + i] = ((const float*)bv)[i];
    }
    __syncthreads();

    const int total = 96 * kk * 4;
    for (int c = tid; c < total; c += 256){
        int jb = c >> 2, ol = c & 3;
        int j0 = jb * 8;
        int t  = j0 / 768;
        int i0 = j0 - t * 768;
        ushort tmp[8];
        #pragma unroll
        for (int jj = 0; jj < 8; ++jj)
            tmp[jj] = lds[ol*rowlen + (i0 + jj)*kk + t];
        int o = ob*4 + ol;
        __builtin_memcpy(Bp + (size_t)jb*6144 + (size_t)o*8, tmp, 16);
    }
}

// ---------------------------------------------------------------------------
// Kernel 2b: features -> bf16 A-source buffer.
// ---------------------------------------------------------------------------
__global__ void cvtA_kernel(const void* __restrict__ feat, ushort* __restrict__ featbf,
                            const int* __restrict__ flag){
    const int bfm = *flag;
    int idx = blockIdx.x*256 + threadIdx.x;
    const int TOT = BB*LL*DD/8;
    if (idx >= TOT) return;
    if (bfm){
        __builtin_memcpy(featbf + (size_t)idx*8, (const ushort*)feat + (size_t)idx*8, 16);
    } else {
        float t8[8];
        __builtin_memcpy(t8,     (const float*)feat + (size_t)idx*8,     16);
        __builtin_memcpy(t8 + 4, (const float*)feat + (size_t)idx*8 + 4, 16);
        ushort o8[8];
        #pragma unroll
        for (int j = 0; j < 8; ++j) o8[j] = f2bf(t8[j]);
        __builtin_memcpy(featbf + (size_t)idx*8, o8, 16);
    }
}

// ---------------------------------------------------------------------------
// Kernel 3: unigram copy + zero invalid + valid flags (native dtype).
// ---------------------------------------------------------------------------
__global__ void fill_kernel(const void* __restrict__ feat, const int* __restrict__ offs,
                            void* __restrict__ out, const int* __restrict__ flag){
    const int bfm = *flag;
    int idx = blockIdx.x*256 + threadIdx.x;
    const int TOT = BB*SS*192;
    if (idx >= TOT) return;
    int b = idx / (SS*192);
    int r = idx - b*(SS*192);
    int s = r / 192;
    int c = r - s*192;
    int c0  = offs[b*9 + 1];
    int tot = offs[b*9 + 8];
    if (bfm){
        if (c < 96){
            ushort* dst = (ushort*)out + ((size_t)b*SS + s)*768 + c*8;
            if (s < c0){
                const ushort* srcp = (const ushort*)feat + ((size_t)b*LL + s + 1)*768 + c*8;
                __builtin_memcpy(dst, srcp, 16);
            } else if (s >= tot){
                const ushort z[8] = {0,0,0,0,0,0,0,0};
                __builtin_memcpy(dst, z, 16);
            }
        }
        if (c == 0)
            ((ushort*)out)[(size_t)BB*SS*768 + (size_t)b*SS + s] = (s < tot) ? (ushort)0x3F80 : (ushort)0;
    } else {
        float* dst = (float*)out + ((size_t)b*SS + s)*768 + c*4;
        if (s < c0){
            const float* srcp = (const float*)feat + ((size_t)b*LL + s + 1)*768 + c*4;
            __builtin_memcpy(dst, srcp, 16);
        } else if (s >= tot){
            const float z[4] = {0.f,0.f,0.f,0.f};
            __builtin_memcpy(dst, z, 16);
        }
        if (c == 0)
            ((float*)out)[(size_t)BB*SS*768 + (size_t)b*SS + s] = (s < tot) ? 1.0f : 0.0f;
    }
}

// ---------------------------------------------------------------------------
// Kernel 4: tile-list GEMM, software-pipelined double-buffered LDS B.
// Per chunk: issue next B global loads -> compute current -> ds_write next ->
// one barrier. A per-lane direct loads (featbf L2-resident), single-buffered.
// ---------------------------------------------------------------------------
__global__ __launch_bounds__(256) void conv_gemm3(const ushort* __restrict__ featbf,
        const ushort* __restrict__ BpAll, const float* __restrict__ biasF,
        const int* __restrict__ pfx, const int* __restrict__ amap,
        const int* __restrict__ omap, const int* __restrict__ tiles,
        void* __restrict__ out, const int* __restrict__ flag){
    const size_t PRE[7] = {0, 2, 5, 9, 14, 20, 27};
    const int tv = tiles[blockIdx.x];
    if (tv < 0) return;
    const int kkidx = (tv >> 16) & 255;
    const int mt    = (tv >> 8) & 255;
    const int nt    = tv & 255;
    const int kk = kkidx + 2;
    const int Mtot = pfx[kkidx*33 + 32];
    const int m0 = mt * 128;
    const int n0 = nt * 128;
    const int bfm = *flag;

    __shared__ ushort Bs[2][8192];        // 2 x 16 KB

    const int tid  = threadIdx.x;
    const int wv   = tid >> 6;
    const int wvm  = wv >> 1;
    const int wvn  = wv & 1;
    const int lane = tid & 63;
    const int quad = lane >> 4;
    const int l15  = lane & 15;

    const ushort* Abase[4];
    #pragma unroll
    for (int sm = 0; sm < 4; ++sm){
        int r = kkidx*MAXM + m0 + wvm*64 + sm*16 + l15;
        Abase[sm] = featbf + (size_t)amap[r]*768 + quad*8;
    }

    floatx4 acc[4][4];
    #pragma unroll
    for (int sn = 0; sn < 4; ++sn){
        float bv = biasF[kkidx*768 + n0 + wvn*64 + sn*16 + l15];
        #pragma unroll
        for (int sm = 0; sm < 4; ++sm){
            acc[sm][sn][0] = bv; acc[sm][sn][1] = bv;
            acc[sm][sn][2] = bv; acc[sm][sn][3] = bv;
        }
    }

    const ushort* BkkBase = BpAll + PRE[kkidx]*589824;
    const int nchunks = kk * 12;          // K / 64

    ushort stg[4][8];
    bf16x8 areg[2][4];

    // ---- prologue: B(0) global->stg->LDS, A(0)->areg ----
    #pragma unroll
    for (int i = 0; i < 4; ++i){
        int c = i*256 + tid, p = c >> 7, off = c & 127;
        __builtin_memcpy(stg[i], BkkBase + (size_t)p*6144 + (size_t)(n0 + off)*8, 16);
    }
    #pragma unroll
    for (int ks = 0; ks < 2; ++ks)
        #pragma unroll
        for (int sm = 0; sm < 4; ++sm)
            __builtin_memcpy(&areg[ks][sm], Abase[sm] + ks*32, 16);
    #pragma unroll
    for (int i = 0; i < 4; ++i)
        __builtin_memcpy(&Bs[0][(i*256 + tid)*8], stg[i], 16);
    __syncthreads();

    for (int ch = 0; ch < nchunks; ++ch){
        const int cur = ch & 1;
        const bool more = (ch + 1 < nchunks);
        if (more){
            const int jb0 = (ch + 1) * 8;
            #pragma unroll
            for (int i = 0; i < 4; ++i){
                int c = i*256 + tid, p = c >> 7, off = c & 127;
                __builtin_memcpy(stg[i], BkkBase + (size_t)(jb0 + p)*6144 + (size_t)(n0 + off)*8, 16);
            }
        }
        // ---- compute chunk ch from Bs[cur] + areg ----
        #pragma unroll
        for (int ks = 0; ks < 2; ++ks){
            const int pl = ks*4 + quad;
            bf16x8 bfr[4];
            #pragma unroll
            for (int sn = 0; sn < 4; ++sn)
                __builtin_memcpy(&bfr[sn], &Bs[cur][pl*1024 + (wvn*64 + sn*16 + l15)*8], 16);
            #pragma unroll
            for (int sm = 0; sm < 4; ++sm)
                #pragma unroll
                for (int sn = 0; sn < 4; ++sn)
                    acc[sm][sn] = __builtin_amdgcn_mfma_f32_16x16x32_bf16(
                        areg[ks][sm], bfr[sn], acc[sm][sn], 0, 0, 0);
        }
        if (more){
            #pragma unroll
            for (int i = 0; i < 4; ++i)
                __builtin_memcpy(&Bs[cur ^ 1][(i*256 + tid)*8], stg[i], 16);
            const int koff = (ch + 1) * 64;
            #pragma unroll
            for (int ks = 0; ks < 2; ++ks)
                #pragma unroll
                for (int sm = 0; sm < 4; ++sm)
                    __builtin_memcpy(&areg[ks][sm], Abase[sm] + koff + ks*32, 16);
        }
        __syncthreads();
    }

    // ---- epilogue: scatter rows to packed span slots ----
    #pragma unroll
    for (int sm = 0; sm < 4; ++sm){
        #pragma unroll
        for (int rr = 0; rr < 4; ++rr){
            int r = m0 + wvm*64 + sm*16 + quad*4 + rr;
            if (r < Mtot){
                int slot = omap[kkidx*MAXM + r];
                if (bfm){
                    ushort* oh = (ushort*)out;
                    #pragma unroll
                    for (int sn = 0; sn < 4; ++sn)
                        oh[(size_t)slot*768 + n0 + wvn*64 + sn*16 + l15] = f2bf(acc[sm][sn][rr]);
                } else {
                    float* of = (float*)out;
                    #pragma unroll
                    for (int sn = 0; sn < 4; ++sn)
                        of[(size_t)slot*768 + n0 + wvn*64 + sn*16 + l15] = acc[sm][sn][rr];
                }
            }
        }
    }
}

// ---------------------------------------------------------------------------
// Fallback (workspace too small): direct-from-raw-weights GEMM. Slow, correct.
// ---------------------------------------------------------------------------
__global__ __launch_bounds__(256) void conv_gemm_direct(const void* __restrict__ feat,
        const int* __restrict__ offs, void* __restrict__ out, const int* __restrict__ flag,
        const void* w2, const void* w3, const void* w4, const void* w5,
        const void* w6, const void* w7, const void* w8,
        const void* b2, const void* b3, const void* b4, const void* b5,
        const void* b6, const void* b7, const void* b8){
    const int bfm = *flag;
    const int kkidx = blockIdx.y;
    const int kk = kkidx + 2;
    const int b = blockIdx.z;
    const void* w  = kkidx==0?w2:kkidx==1?w3:kkidx==2?w4:kkidx==3?w5:kkidx==4?w6:kkidx==5?w7:w8;
    const void* bv = kkidx==0?b2:kkidx==1?b3:kkidx==2?b4:kkidx==3?b5:kkidx==4?b6:kkidx==5?b7:b8;

    const int off_j = offs[b*9 + kk - 1];
    const int cnt   = offs[b*9 + kk] - off_j;
    const int mt = blockIdx.x / 12;
    const int nt = blockIdx.x - mt*12;
    const int m0 = mt * 64;
    if (m0 >= cnt) return;
    const int n0 = nt * 64;

    const int tid  = threadIdx.x;
    const int wvv  = tid >> 6;
    const int lane = tid & 63;
    const int quad = lane >> 4;
    const int l15  = lane & 15;

    int row  = m0 + wvv*16 + l15;
    int arow = row < cnt ? row : cnt - 1;
    const size_t abase = ((size_t)b*LL + arow + 1)*768 + quad*8;

    floatx4 acc[4];
    #pragma unroll
    for (int cg = 0; cg < 4; ++cg){
        float bb = bfm ? bf2f(((const ushort*)bv)[n0 + cg*16 + l15])
                       : ((const float*)bv)[n0 + cg*16 + l15];
        acc[cg][0] = bb; acc[cg][1] = bb; acc[cg][2] = bb; acc[cg][3] = bb;
    }

    const int steps = kk * 24;
    for (int s = 0; s < steps; ++s){
        bf16x8 a;
        if (bfm){
            __builtin_memcpy(&a, (const ushort*)feat + abase + s*32, 16);
        } else {
            float t8[8];
            __builtin_memcpy(t8,     (const float*)feat + abase + s*32,     16);
            __builtin_memcpy(t8 + 4, (const float*)feat + abase + s*32 + 4, 16);
            ushort o8[8];
            #pragma unroll
            for (int j = 0; j < 8; ++j) o8[j] = f2bf(t8[j]);
            __builtin_memcpy(&a, o8, 16);
        }
        int j0 = s*32 + quad*8;
        int t  = j0 / 768;
        int i0 = j0 - t*768;
        #pragma unroll
        for (int cg = 0; cg < 4; ++cg){
            int o = n0 + cg*16 + l15;
            size_t wbase = (size_t)o*(DD*kk) + (size_t)i0*kk + t;
            ushort tmp[8];
            if (bfm){
                const ushort* wp = (const ushort*)w + wbase;
                #pragma unroll
                for (int jj = 0; jj < 8; ++jj) tmp[jj] = wp[(size_t)jj*kk];
            } else {
                const float* wp = (const float*)w + wbase;
                #pragma unroll
                for (int jj = 0; jj < 8; ++jj) tmp[jj] = f2bf(wp[(size_t)jj*kk]);
            }
            bf16x8 bfr;
            __builtin_memcpy(&bfr, tmp, 16);
            acc[cg] = __builtin_amdgcn_mfma_f32_16x16x32_bf16(a, bfr, acc[cg], 0, 0, 0);
        }
    }

    const int rbase = m0 + wvv*16 + quad*4;
    if (bfm){
        ushort* outh = (ushort*)out;
        #pragma unroll
        for (int cg = 0; cg < 4; ++cg)
            #pragma unroll
            for (int rr = 0; rr < 4; ++rr){
                int grow = rbase + rr;
                if (grow < cnt)
                    outh[((size_t)b*SS + off_j + grow)*768 + n0 + cg*16 + l15] = f2bf(acc[cg][rr]);
            }
    } else {
        float* outf = (float*)out;
        #pragma unroll
        for (int cg = 0; cg < 4; ++cg)
            #pragma unroll
            for (int rr = 0; rr < 4; ++rr){
                int grow = rbase + rr;
                if (grow < cnt)
                    outf[((size_t)b*SS + off_j + grow)*768 + n0 + cg*16 + l15] = acc[cg][rr];
            }
    }
}

// ---------------------------------------------------------------------------
extern "C" void kernel_launch(void* const* d_in, const int* in_sizes, int n_in,
                              void* d_out, int out_size, void* d_ws, size_t ws_size,
                              hipStream_t stream) {
    const void* feat = d_in[0];
    const int*  mask = (const int*)d_in[1];

    const void* w[7]  = {0,0,0,0,0,0,0};
    const void* bs[7] = {0,0,0,0,0,0,0};
    int bi = 0;
    for (int i = 3; i < n_in; ++i){
        if (in_sizes[i] == 768){
            if (bi < 7) bs[bi++] = d_in[i];
        } else {
            int kk = in_sizes[i] / 589824;
            if (kk >= 2 && kk <= 8) w[kk-2] = d_in[i];
        }
    }

    // ws layout (compact)
    char* ws = (char*)d_ws;
    int*    flag    = (int*)ws;                         // @0
    int*    offs    = (int*)(ws + 64);                  // 288*4 = 1152 -> 1216
    int*    pfx     = (int*)(ws + 1216);                // 231*4 = 924  -> 2140
    float*  biasF   = (float*)(ws + 2144);              // 21504        -> 23648
    int*    amap    = (int*)(ws + 23648);               // 179200       -> 202848
    int*    omap    = (int*)(ws + 202848);              // 179200       -> 382048
    int*    tiles   = (int*)(ws + 382048);              // 9600         -> 391648
    ushort* featbf  = (ushort*)(ws + 391648);           // 9830400      -> 10222048
    ushort* Bp      = (ushort*)(ws + 10222048);         // 41287680     -> 51509728
    const size_t FULL_BYTES = 51509728ull;
    const int use_full = (ws_size >= FULL_BYTES) ? 1 : 0;

    hipLaunchKernelGGL(prep_kernel, dim3(1), dim3(256), 0, stream,
                       (const unsigned int*)feat, mask, flag, offs, pfx,
                       amap, omap, tiles, use_full);

    if (use_full){
        hipLaunchKernelGGL(repack2_kernel, dim3(192, 7), dim3(256), 0, stream,
                           w[0], w[1], w[2], w[3], w[4], w[5], w[6],
                           bs[0], bs[1], bs[2], bs[3], bs[4], bs[5], bs[6],
                           Bp, biasF, flag);
        hipLaunchKernelGGL(cvtA_kernel, dim3(2400), dim3(256), 0, stream, feat, featbf, flag);
    }

    hipLaunchKernelGGL(fill_kernel, dim3((BB*SS*192 + 255)/256), dim3(256), 0, stream,
                       feat, offs, d_out, flag);

    if (use_full){
        hipLaunchKernelGGL(conv_gemm3, dim3(NTILES_MAX), dim3(256), 0, stream,
                           featbf, Bp, biasF, pfx, amap, omap, tiles, d_out, flag);
    } else {
        hipLaunchKernelGGL(conv_gemm_direct, dim3(48, 7, BB), dim3(256), 0, stream,
                           feat, offs, d_out, flag,
                           w[0], w[1], w[2], w[3], w[4], w[5], w[6],
                           bs[0], bs[1], bs[2], bs[3], bs[4], bs[5], bs[6]);
    }
}